// Round 14
// baseline (8724.543 us; speedup 1.0000x reference)
//
#include <hip/hip_runtime.h>
#include <stdint.h>

typedef unsigned long long u64;
typedef u64 u64x2 __attribute__((ext_vector_type(2)));

#define VOCAB 128
#define RD 128
#define DM 1024
#define NFF 6
#define BATCH 64
#define TSTEPS 512
#define THR 512   // threads per block; thread owns cols c2*512+tid, c2=0,1

// ---------------------------------------------------------------------------
// ws layout (bytes):
//   [0, 786432)       ffs  [L][c2][i][tid][2] u64, DMA chunks for 512 thr:
//                     u64 idx = (((L*2+c2)*8+i)*512+tid)*2 + s
//                     -> one load instr (L,c2,i) = 64 lanes x 16 B contiguous.
//   [786432, +2048)   ebits [v][2] u64
//   [788480, +2048)   headb [v][2] u64
//   [790528, +512)    losses [64] double
// ---------------------------------------------------------------------------
#define OFF_EB    786432
#define OFF_HB    788480
#define OFF_LOSS  790528

// lgkm-only barrier: LDS h-writes drained; global weight prefetch (vmcnt)
// stays in flight across the barrier.
#define BARRIER()                                            \
    do {                                                     \
        asm volatile("s_waitcnt lgkmcnt(0)" ::: "memory");   \
        __builtin_amdgcn_s_barrier();                        \
    } while (0)

// Pack ff sign bits into 512-thread chunk layout.
// bit b of word (L,w,j) = (ff[L][w*64+b][j] < 0)  (1 => -1)
__global__ void pack_ff(const float* __restrict__ ff, u64* __restrict__ ffs) {
    int wid  = blockIdx.x * (blockDim.x >> 6) + (threadIdx.x >> 6); // 0..1535
    int lane = threadIdx.x & 63;
    int jt = wid & 15;
    int w  = (wid >> 4) & 15;  // word 0..15
    int L  = wid >> 8;         // layer
    int j  = jt * 64 + lane;   // column
    const float* src = ff + ((size_t)(L * DM) + w * 64) * DM + j;
    u64 word = 0;
#pragma unroll
    for (int b = 0; b < 64; ++b) {
        float v = src[(size_t)b * DM];
        word |= (u64)(v < 0.0f) << b;
    }
    int c2 = j >> 9, t = j & 511, i = w >> 1, s = w & 1;
    ffs[((((L * 2 + c2) * 8 + i) * 512 + t) << 1) + s] = word;
}

// Pack embed rows and head columns (tiny).
__global__ void pack_small(const float* __restrict__ emb, const float* __restrict__ head,
                           u64* __restrict__ eb, u64* __restrict__ hb) {
    int tid = threadIdx.x; // 0..255
    if (tid < 128) {
        int v = tid;
        for (int wd = 0; wd < 2; ++wd) {
            u64 word = 0;
            for (int l = 0; l < 64; ++l)
                word |= (u64)(emb[v * RD + wd * 64 + l] < 0.0f) << l;
            eb[v * 2 + wd] = word;
        }
    } else {
        int v = tid - 128;
        for (int wd = 0; wd < 2; ++wd) {
            u64 word = 0;
            for (int l = 0; l < 64; ++l)
                word |= (u64)(head[(wd * 64 + l) * VOCAB + v] < 0.0f) << l;
            hb[v * 2 + wd] = word;
        }
    }
}

// Issue 16 coalesced dwordx4 loads for layer L into BUF[2][16] (2 cols).
#define PF(BUF, L)                                                       \
    do {                                                                 \
        _Pragma("unroll")                                                \
        for (int c2_ = 0; c2_ < 2; ++c2_) {                              \
            _Pragma("unroll")                                            \
            for (int i_ = 0; i_ < 8; ++i_) {                             \
                u64x2 v_ = wsrc[((((L) * 2 + c2_) * 8 + i_) << 9) + tid];\
                BUF[c2_][2 * i_] = v_.x; BUF[c2_][2 * i_ + 1] = v_.y;    \
            }                                                            \
        }                                                                \
    } while (0)

// One streamed layer: h from hx[P], weights from BUF, result -> hx[P^1].
#define COMP(BUF, L, P)                                                  \
    do {                                                                 \
        const ulonglong2* hp_ = (const ulonglong2*)hx[P];                \
        int a0_ = 0, a1_ = 0;                                            \
        _Pragma("unroll")                                                \
        for (int q_ = 0; q_ < 8; ++q_) {                                 \
            ulonglong2 hv_ = hp_[q_]; /* broadcast ds_read_b128 */       \
            a0_ += __popcll(hv_.x ^ BUF[0][2 * q_]) +                    \
                   __popcll(hv_.y ^ BUF[0][2 * q_ + 1]);                 \
            a1_ += __popcll(hv_.x ^ BUF[1][2 * q_]) +                    \
                   __popcll(hv_.y ^ BUF[1][2 * q_ + 1]);                 \
        }                                                                \
        u64 m0_ = __ballot(a0_ >= cthr[L][0]);                           \
        u64 m1_ = __ballot(a1_ >= cthr[L][1]);                           \
        if (lane == 0) { hx[(P) ^ 1][wv] = m0_; hx[(P) ^ 1][8 + wv] = m1_; } \
        BARRIER();                                                       \
    } while (0)

// One full step. X = buffer holding THIS step's layer 0; Y = other buffer.
// Leaves next step's layer 0 in Y.
#define STEP(X, Y, T)                                                    \
    do {                                                                 \
        const int tok_ = toks[T];                                        \
        u64 enew_ = 0;                                                   \
        if (wv == 0 && lane < 2) enew_ = eb[tok_ * 2 + lane];            \
        PF(Y, 1); COMP(X, 0, 0);                                         \
        PF(X, 2); COMP(Y, 1, 1);                                         \
        PF(Y, 3); COMP(X, 2, 0);                                         \
        PF(X, 4); COMP(Y, 3, 1);                                         \
        PF(Y, 0); COMP(X, 4, 0);   /* PF layer 0 for next step */        \
        /* layer 5 from LDS: h in hx[1] -> hx[0] */                      \
        {                                                                \
            const ulonglong2* hp_ = (const ulonglong2*)hx[1];            \
            int a0_ = 0, a1_ = 0;                                        \
            _Pragma("unroll")                                            \
            for (int q_ = 0; q_ < 8; ++q_) {                             \
                ulonglong2 hv_ = hp_[q_];                                \
                ulonglong2 w0_ = *(const ulonglong2*)wlds[q_][tid];      \
                ulonglong2 w1_ = *(const ulonglong2*)wlds[q_][512 + tid];\
                a0_ += __popcll(hv_.x ^ w0_.x) + __popcll(hv_.y ^ w0_.y);\
                a1_ += __popcll(hv_.x ^ w1_.x) + __popcll(hv_.y ^ w1_.y);\
            }                                                            \
            u64 m0_ = __ballot(a0_ >= cthr[5][0]);                       \
            u64 m1_ = __ballot(a1_ >= cthr[5][1]);                       \
            if (lane == 0) { hx[0][wv] = m0_; hx[0][8 + wv] = m1_; }     \
            BARRIER();                                                   \
        }                                                                \
        /* head + log-softmax + loss + splice (wave 0); h5 in hx[0] */   \
        if (wv == 0) {                                                   \
            u64 ra_ = hx[0][14], rb_ = hx[0][15];                        \
            u64 h0a_ = hbL[lane * 2 + 0],        h0b_ = hbL[lane * 2 + 1];        \
            u64 h1a_ = hbL[(lane + 64) * 2 + 0], h1b_ = hbL[(lane + 64) * 2 + 1]; \
            int d0_ = 128 - 2 * (__popcll(ra_ ^ h0a_) + __popcll(rb_ ^ h0b_));    \
            int d1_ = 128 - 2 * (__popcll(ra_ ^ h1a_) + __popcll(rb_ ^ h1b_));    \
            float l0_ = (float)d0_ * (1.0f / 16.0f);                     \
            float l1_ = (float)d1_ * (1.0f / 16.0f);                     \
            float mx_ = fmaxf(l0_, l1_);                                 \
            _Pragma("unroll")                                            \
            for (int s_ = 32; s_ >= 1; s_ >>= 1) mx_ = fmaxf(mx_, __shfl_xor(mx_, s_)); \
            float se_ = __expf(l0_ - mx_) + __expf(l1_ - mx_);           \
            _Pragma("unroll")                                            \
            for (int s_ = 32; s_ >= 1; s_ >>= 1) se_ += __shfl_xor(se_, s_); \
            int   tl_   = tok_ & 63;                                     \
            float la_   = __shfl(l0_, tl_);                              \
            float lb_   = __shfl(l1_, tl_);                              \
            float ltok_ = (tok_ >> 6) ? lb_ : la_;                       \
            lacc += (double)(mx_ + __logf(se_) - ltok_);                 \
            if (lane < 2) hx[0][14 + lane] = enew_;                      \
        }                                                                \
        BARRIER();                                                       \
    } while (0)

// Main recurrent kernel: one block (one CU) per batch row, 512 threads,
// 2 waves/SIMD (waves_per_eu(2,2) -> 256-reg budget x 8 waves = full RF).
// Layer 5 LDS-resident; layers 0-4 streamed via ping-pong register
// double-buffer with one-layer-ahead prefetch crossing lgkm-only barriers.
__global__ void
__attribute__((amdgpu_flat_work_group_size(THR, THR), amdgpu_waves_per_eu(2, 2)))
brnn_main(const int* __restrict__ tokens,
          const float* __restrict__ initial_lat,
          const float* __restrict__ thr_lat,
          const u64* __restrict__ ffs,
          const u64* __restrict__ eb,
          const u64* __restrict__ hb,
          double* __restrict__ losses)
{
    const int b    = blockIdx.x;
    const int tid  = threadIdx.x;
    const int lane = tid & 63;
    const int wv   = tid >> 6; // 0..7

    __shared__ __align__(16) u64 wlds[8][1024][2]; // layer 5: 128 KB
    __shared__ __align__(16) u64 hx[2][16];
    __shared__ u64 hbL[2 * VOCAB];

    const u64x2* wsrc = (const u64x2*)ffs;

    // --- one-time: stage layer 5 into LDS from its chunks ---
#pragma unroll
    for (int c2 = 0; c2 < 2; ++c2)
#pragma unroll
        for (int i = 0; i < 8; ++i) {
            u64x2 v = wsrc[(((5 * 2 + c2) * 8 + i) << 9) + tid];
            wlds[i][c2 * 512 + tid][0] = v.x;
            wlds[i][c2 * 512 + tid][1] = v.y;
        }

    // thresholds -> popcount cutoffs:  bit(-1) <=> pre < thr  <=>  acc >= cthr
    int cthr[NFF][2];
#pragma unroll
    for (int L = 0; L < NFF; ++L)
#pragma unroll
        for (int c2 = 0; c2 < 2; ++c2) {
            int th = (int)rintf(thr_lat[L * DM + c2 * 512 + tid]); // round-half-even
            cthr[L][c2] = ((DM - th) >> 1) + 1;
        }

    if (tid < 2 * VOCAB) hbL[tid] = hb[tid];

    // --- init h = sign(initial_lat) into hx[0] ---
#pragma unroll
    for (int c2 = 0; c2 < 2; ++c2) {
        u64 m = __ballot(initial_lat[c2 * 512 + tid] < 0.0f);
        if (lane == 0) hx[0][c2 * 8 + wv] = m;
    }

    u64 cA[2][16], cB[2][16];
    PF(cA, 0);
    __syncthreads(); // one-time full barrier (wlds + hx + hbL visible)

    const int* toks = tokens + b * TSTEPS;
    double lacc = 0.0;

    for (int t = 0; t < TSTEPS; t += 2) {
        STEP(cA, cB, t);     // leaves next layer 0 in cB
        STEP(cB, cA, t + 1); // leaves next layer 0 in cA
    }

    if (tid == 0) losses[b] = lacc;
}

__global__ void reduce_loss(const double* __restrict__ losses, float* __restrict__ out) {
    int lane = threadIdx.x; // 64 threads, 1 wave
    double v = losses[lane];
#pragma unroll
    for (int s = 32; s >= 1; s >>= 1) v += __shfl_down(v, s);
    if (lane == 0) out[0] = (float)(v * (1.0 / ((double)BATCH * (double)TSTEPS)));
}

extern "C" void kernel_launch(void* const* d_in, const int* in_sizes, int n_in,
                              void* d_out, int out_size, void* d_ws, size_t ws_size,
                              hipStream_t stream) {
    const int*   tokens  = (const int*)d_in[0];   // (64, 512) int32
    const float* initial = (const float*)d_in[1]; // (1024,)
    const float* embed   = (const float*)d_in[2]; // (128, 128)
    const float* ff      = (const float*)d_in[3]; // (6, 1024, 1024)
    const float* head    = (const float*)d_in[4]; // (128, 128)
    const float* thrl    = (const float*)d_in[5]; // (6, 1024)

    char* ws = (char*)d_ws;
    u64*    ffs    = (u64*)ws;                 // 786432 B
    u64*    eb     = (u64*)(ws + OFF_EB);      // 2048 B
    u64*    hb     = (u64*)(ws + OFF_HB);      // 2048 B
    double* losses = (double*)(ws + OFF_LOSS); // 512 B

    pack_ff<<<384, 256, 0, stream>>>(ff, ffs);
    pack_small<<<1, 256, 0, stream>>>(embed, head, eb, hb);
    brnn_main<<<BATCH, THR, 0, stream>>>(tokens, initial, thrl, ffs, eb, hb, losses);
    reduce_loss<<<1, 64, 0, stream>>>(losses, (float*)d_out);
}

// Round 15
// 5806.467 us; speedup vs baseline: 1.5026x; 1.5026x over previous
//
#include <hip/hip_runtime.h>
#include <stdint.h>

typedef unsigned long long u64;
typedef u64 u64x2 __attribute__((ext_vector_type(2)));

#define VOCAB 128
#define RD 128
#define DM 1024
#define NFF 6
#define BATCH 64
#define TSTEPS 512
#define THR 512   // threads per block; thread owns cols tid and tid+512

// ---------------------------------------------------------------------------
// ws layout (bytes):
//   [0, 786432)       ffs  [L][c2][i][tid][2] u64, DMA chunks for 512 thr:
//                     u64 idx = (((L*2+c2)*8+i)*512+tid)*2 + s
//                     -> one load instr (L,c2,i) = 64 lanes x 16 B contiguous.
//   [786432, +2048)   ebits [v][2] u64
//   [788480, +2048)   headb [v][2] u64
//   [790528, +512)    losses [64] double
// ---------------------------------------------------------------------------
#define OFF_EB    786432
#define OFF_HB    788480
#define OFF_LOSS  790528

// lgkm-only barrier: LDS h-writes drained; global weight prefetch (vmcnt)
// stays in flight across the barrier.
#define BARRIER()                                            \
    do {                                                     \
        asm volatile("s_waitcnt lgkmcnt(0)" ::: "memory");   \
        __builtin_amdgcn_s_barrier();                        \
    } while (0)

// Pack ff sign bits into 512-thread chunk layout.
// bit b of word (L,w,j) = (ff[L][w*64+b][j] < 0)  (1 => -1)
__global__ void pack_ff(const float* __restrict__ ff, u64* __restrict__ ffs) {
    int wid  = blockIdx.x * (blockDim.x >> 6) + (threadIdx.x >> 6); // 0..1535
    int lane = threadIdx.x & 63;
    int jt = wid & 15;
    int w  = (wid >> 4) & 15;  // word 0..15
    int L  = wid >> 8;         // layer
    int j  = jt * 64 + lane;   // column
    const float* src = ff + ((size_t)(L * DM) + w * 64) * DM + j;
    u64 word = 0;
#pragma unroll
    for (int b = 0; b < 64; ++b) {
        float v = src[(size_t)b * DM];
        word |= (u64)(v < 0.0f) << b;
    }
    int c2 = j >> 9, t = j & 511, i = w >> 1, s = w & 1;
    ffs[((((L * 2 + c2) * 8 + i) * 512 + t) << 1) + s] = word;
}

// Pack embed rows and head columns (tiny).
__global__ void pack_small(const float* __restrict__ emb, const float* __restrict__ head,
                           u64* __restrict__ eb, u64* __restrict__ hb) {
    int tid = threadIdx.x; // 0..255
    if (tid < 128) {
        int v = tid;
        for (int wd = 0; wd < 2; ++wd) {
            u64 word = 0;
            for (int l = 0; l < 64; ++l)
                word |= (u64)(emb[v * RD + wd * 64 + l] < 0.0f) << l;
            eb[v * 2 + wd] = word;
        }
    } else {
        int v = tid - 128;
        for (int wd = 0; wd < 2; ++wd) {
            u64 word = 0;
            for (int l = 0; l < 64; ++l)
                word |= (u64)(head[(wd * 64 + l) * VOCAB + v] < 0.0f) << l;
            hb[v * 2 + wd] = word;
        }
    }
}

// Issue 8 coalesced dwordx4 loads for chunk (L, C2) into BUF[16].
#define PF1(BUF, L, C2)                                                  \
    do {                                                                 \
        _Pragma("unroll")                                                \
        for (int i_ = 0; i_ < 8; ++i_) {                                 \
            u64x2 v_ = wsrc[((((L) * 2 + (C2)) * 8 + i_) << 9) + tid];   \
            BUF[2 * i_] = v_.x; BUF[2 * i_ + 1] = v_.y;                  \
        }                                                                \
    } while (0)

// One streamed layer L (literal): consume p0/p1, re-issue them for layer PFL.
// h read from hx[L&1], result written to hx[(L&1)^1].
#define SLAYER(L, PFL)                                                   \
    do {                                                                 \
        const ulonglong2* hp_ = (const ulonglong2*)hx[(L) & 1];          \
        ulonglong2 h0_ = hp_[0], h1_ = hp_[1], h2_ = hp_[2], h3_ = hp_[3], \
                   h4_ = hp_[4], h5_ = hp_[5], h6_ = hp_[6], h7_ = hp_[7]; \
        int a0_ = 0;                                                     \
        a0_ += __popcll(h0_.x ^ p0[0])  + __popcll(h0_.y ^ p0[1]);       \
        a0_ += __popcll(h1_.x ^ p0[2])  + __popcll(h1_.y ^ p0[3]);       \
        a0_ += __popcll(h2_.x ^ p0[4])  + __popcll(h2_.y ^ p0[5]);       \
        a0_ += __popcll(h3_.x ^ p0[6])  + __popcll(h3_.y ^ p0[7]);       \
        a0_ += __popcll(h4_.x ^ p0[8])  + __popcll(h4_.y ^ p0[9]);       \
        a0_ += __popcll(h5_.x ^ p0[10]) + __popcll(h5_.y ^ p0[11]);      \
        a0_ += __popcll(h6_.x ^ p0[12]) + __popcll(h6_.y ^ p0[13]);      \
        a0_ += __popcll(h7_.x ^ p0[14]) + __popcll(h7_.y ^ p0[15]);      \
        PF1(p0, PFL, 0);  /* re-issue immediately: in flight ~1 layer */ \
        int a1_ = 0;                                                     \
        a1_ += __popcll(h0_.x ^ p1[0])  + __popcll(h0_.y ^ p1[1]);       \
        a1_ += __popcll(h1_.x ^ p1[2])  + __popcll(h1_.y ^ p1[3]);       \
        a1_ += __popcll(h2_.x ^ p1[4])  + __popcll(h2_.y ^ p1[5]);       \
        a1_ += __popcll(h3_.x ^ p1[6])  + __popcll(h3_.y ^ p1[7]);       \
        a1_ += __popcll(h4_.x ^ p1[8])  + __popcll(h4_.y ^ p1[9]);       \
        a1_ += __popcll(h5_.x ^ p1[10]) + __popcll(h5_.y ^ p1[11]);      \
        a1_ += __popcll(h6_.x ^ p1[12]) + __popcll(h6_.y ^ p1[13]);      \
        a1_ += __popcll(h7_.x ^ p1[14]) + __popcll(h7_.y ^ p1[15]);      \
        PF1(p1, PFL, 1);                                                 \
        u64 m0_ = __ballot(a0_ >= cthr[L][0]);                           \
        u64 m1_ = __ballot(a1_ >= cthr[L][1]);                           \
        if (lane == 0) { hx[((L) & 1) ^ 1][wv] = m0_;                    \
                         hx[((L) & 1) ^ 1][8 + wv] = m1_; }              \
        BARRIER();                                                       \
    } while (0)

// Main recurrent kernel: one block (one CU) per batch row, 512 threads,
// 2 waves/SIMD (TLP hides latency). Layer 5 LDS-resident (128 KB); layers
// 0-4 streamed via per-column chunk ping-pong: each chunk's 8 dwordx4 loads
// are in flight for a full layer before use, crossing lgkm-only barriers.
// Register ask ~112 <= proven 128-grant -> nothing to spill.
__global__ void
__attribute__((amdgpu_flat_work_group_size(THR, THR), amdgpu_waves_per_eu(2, 2)))
brnn_main(const int* __restrict__ tokens,
          const float* __restrict__ initial_lat,
          const float* __restrict__ thr_lat,
          const u64* __restrict__ ffs,
          const u64* __restrict__ eb,
          const u64* __restrict__ hb,
          double* __restrict__ losses)
{
    const int b    = blockIdx.x;
    const int tid  = threadIdx.x;
    const int lane = tid & 63;
    const int wv   = tid >> 6; // 0..7

    __shared__ __align__(16) u64 wlds[8][1024][2]; // layer 5: 128 KB
    __shared__ __align__(16) u64 hx[2][16];
    __shared__ u64 hbL[2 * VOCAB];

    const u64x2* wsrc = (const u64x2*)ffs;

    // --- one-time: stage layer 5 into LDS from its chunks ---
#pragma unroll
    for (int c2 = 0; c2 < 2; ++c2)
#pragma unroll
        for (int i = 0; i < 8; ++i) {
            u64x2 v = wsrc[(((5 * 2 + c2) * 8 + i) << 9) + tid];
            wlds[i][c2 * 512 + tid][0] = v.x;
            wlds[i][c2 * 512 + tid][1] = v.y;
        }

    // thresholds -> popcount cutoffs:  bit(-1) <=> pre < thr  <=>  acc >= cthr
    int cthr[NFF][2];
#pragma unroll
    for (int L = 0; L < NFF; ++L)
#pragma unroll
        for (int c2 = 0; c2 < 2; ++c2) {
            int th = (int)rintf(thr_lat[L * DM + c2 * 512 + tid]); // round-half-even
            cthr[L][c2] = ((DM - th) >> 1) + 1;
        }

    if (tid < 2 * VOCAB) hbL[tid] = hb[tid];

    // --- init h = sign(initial_lat) into hx[0] ---
#pragma unroll
    for (int c2 = 0; c2 < 2; ++c2) {
        u64 m = __ballot(initial_lat[c2 * 512 + tid] < 0.0f);
        if (lane == 0) hx[0][c2 * 8 + wv] = m;
    }

    // chunk ping-pong buffers; prologue: layer 0 chunks in flight
    u64 p0[16], p1[16];
    PF1(p0, 0, 0);
    PF1(p1, 0, 1);
    __syncthreads(); // one-time full barrier (wlds + hx + hbL visible)

    const int* toks = tokens + b * TSTEPS;
    double lacc = 0.0;

    for (int t = 0; t < TSTEPS; ++t) {
        const int tok = toks[t]; // uniform -> scalar load
        u64 enew = 0;
        if (wv == 0 && lane < 2) enew = eb[tok * 2 + lane]; // prefetch

        SLAYER(0, 1);
        SLAYER(1, 2);
        SLAYER(2, 3);
        SLAYER(3, 4);
        SLAYER(4, 0);   // re-issues layer 0 chunks for step t+1

        // --- layer 5 from LDS: h in hx[1] -> hx[0] ---
        {
            const ulonglong2* hp = (const ulonglong2*)hx[1];
            int a0 = 0, a1 = 0;
#pragma unroll
            for (int q = 0; q < 8; ++q) {
                ulonglong2 hv = hp[q]; // broadcast
                ulonglong2 w0 = *(const ulonglong2*)wlds[q][tid];
                ulonglong2 w1 = *(const ulonglong2*)wlds[q][512 + tid];
                a0 += __popcll(hv.x ^ w0.x) + __popcll(hv.y ^ w0.y);
                a1 += __popcll(hv.x ^ w1.x) + __popcll(hv.y ^ w1.y);
            }
            u64 m0 = __ballot(a0 >= cthr[5][0]);
            u64 m1 = __ballot(a1 >= cthr[5][1]);
            if (lane == 0) { hx[0][wv] = m0; hx[0][8 + wv] = m1; }
            BARRIER();
        }

        // --- head + log-softmax + loss + embed splice (wave 0); h5 in hx[0] ---
        if (wv == 0) {
            u64 ra = hx[0][14], rb = hx[0][15];
            u64 h0a = hbL[lane * 2 + 0],        h0b = hbL[lane * 2 + 1];
            u64 h1a = hbL[(lane + 64) * 2 + 0], h1b = hbL[(lane + 64) * 2 + 1];
            int d0 = 128 - 2 * (__popcll(ra ^ h0a) + __popcll(rb ^ h0b));
            int d1 = 128 - 2 * (__popcll(ra ^ h1a) + __popcll(rb ^ h1b));
            float l0 = (float)d0 * (1.0f / 16.0f);
            float l1 = (float)d1 * (1.0f / 16.0f);
            float mx = fmaxf(l0, l1);
#pragma unroll
            for (int s = 32; s >= 1; s >>= 1) mx = fmaxf(mx, __shfl_xor(mx, s));
            float se = __expf(l0 - mx) + __expf(l1 - mx);
#pragma unroll
            for (int s = 32; s >= 1; s >>= 1) se += __shfl_xor(se, s);
            int   tl   = tok & 63;
            float la   = __shfl(l0, tl);
            float lb   = __shfl(l1, tl);
            float ltok = (tok >> 6) ? lb : la;
            lacc += (double)(mx + __logf(se) - ltok);
            // splice x_new read-part = sign(embed[tok]) into words 14,15
            if (lane < 2) hx[0][14 + lane] = enew;
        }
        BARRIER();
    }

    if (tid == 0) losses[b] = lacc;
}

__global__ void reduce_loss(const double* __restrict__ losses, float* __restrict__ out) {
    int lane = threadIdx.x; // 64 threads, 1 wave
    double v = losses[lane];
#pragma unroll
    for (int s = 32; s >= 1; s >>= 1) v += __shfl_down(v, s);
    if (lane == 0) out[0] = (float)(v * (1.0 / ((double)BATCH * (double)TSTEPS)));
}

extern "C" void kernel_launch(void* const* d_in, const int* in_sizes, int n_in,
                              void* d_out, int out_size, void* d_ws, size_t ws_size,
                              hipStream_t stream) {
    const int*   tokens  = (const int*)d_in[0];   // (64, 512) int32
    const float* initial = (const float*)d_in[1]; // (1024,)
    const float* embed   = (const float*)d_in[2]; // (128, 128)
    const float* ff      = (const float*)d_in[3]; // (6, 1024, 1024)
    const float* head    = (const float*)d_in[4]; // (128, 128)
    const float* thrl    = (const float*)d_in[5]; // (6, 1024)

    char* ws = (char*)d_ws;
    u64*    ffs    = (u64*)ws;                 // 786432 B
    u64*    eb     = (u64*)(ws + OFF_EB);      // 2048 B
    u64*    hb     = (u64*)(ws + OFF_HB);      // 2048 B
    double* losses = (double*)(ws + OFF_LOSS); // 512 B

    pack_ff<<<384, 256, 0, stream>>>(ff, ffs);
    pack_small<<<1, 256, 0, stream>>>(embed, head, eb, hb);
    brnn_main<<<BATCH, THR, 0, stream>>>(tokens, initial, thrl, ffs, eb, hb, losses);
    reduce_loss<<<1, 64, 0, stream>>>(losses, (float*)d_out);
}